// Round 1
// baseline (215.387 us; speedup 1.0000x reference)
//
#include <hip/hip_runtime.h>
#include <math.h>

#define T_TOKENS 16384
#define HDIM 2048
#define NE 64
#define NE2 128
#define KTOP 8

// ---------------------------------------------------------------------------
// Kernel 1: weight[t][e] = logits_t + softplus(logits_n) * noise[e]
// GEMM C[16384,128] = X[16384,2048] * Wcat^T, fp32 vector FMA, LDS tiled.
// BM=64 tokens, BN=128 (all 128 rows: 64 transform + 64 noise), BK=32.
// Block = 512 threads, grid = 256 blocks.
// ---------------------------------------------------------------------------
__global__ __launch_bounds__(512) void k_gemm(const float* __restrict__ X,
                                              const float* __restrict__ Wt,
                                              const float* __restrict__ Wn,
                                              const float* __restrict__ noise,
                                              float* __restrict__ weight) {
    __shared__ float smem[8192];          // 32 KB
    float* xs = smem;                     // [64][32]  layout [m][k]
    float* wsh = smem + 64 * 32;          // [32][128] layout [k][n]

    const int tid = threadIdx.x;
    const int t0 = blockIdx.x * 64;
    const int tn = tid & 31;              // expert group: experts tn*4..tn*4+3
    const int tm = tid >> 5;              // token group [0,16): tokens tm*4..tm*4+3

    float4 acc[4];
    #pragma unroll
    for (int i = 0; i < 4; ++i) acc[i] = make_float4(0.f, 0.f, 0.f, 0.f);

    const int xm = tid >> 3;              // 0..63
    const int xkg = tid & 7;              // 0..7 (float4 slot)

    for (int k0 = 0; k0 < HDIM; k0 += 32) {
        __syncthreads();
        // stage X tile: 64 tokens x 32 k  (coalesced float4)
        {
            float4 v = *(const float4*)(X + (size_t)(t0 + xm) * HDIM + k0 + xkg * 4);
            *(float4*)(xs + xm * 32 + xkg * 4) = v;
        }
        // stage W tile: 128 rows x 32 k, transposed into [k][n]
        #pragma unroll
        for (int r = 0; r < 2; ++r) {
            int f = tid + r * 512;
            int n = f >> 3;               // 0..127
            int kg = f & 7;
            const float* wrow = (n < NE) ? (Wt + (size_t)n * HDIM)
                                         : (Wn + (size_t)(n - NE) * HDIM);
            float4 v = *(const float4*)(wrow + k0 + kg * 4);
            wsh[(kg * 4 + 0) * 128 + n] = v.x;
            wsh[(kg * 4 + 1) * 128 + n] = v.y;
            wsh[(kg * 4 + 2) * 128 + n] = v.z;
            wsh[(kg * 4 + 3) * 128 + n] = v.w;
        }
        __syncthreads();

        #pragma unroll
        for (int kk = 0; kk < 32; kk += 4) {
            float4 xv[4], wv[4];
            #pragma unroll
            for (int i = 0; i < 4; ++i)
                xv[i] = *(const float4*)(xs + (tm * 4 + i) * 32 + kk);
            #pragma unroll
            for (int j = 0; j < 4; ++j)
                wv[j] = *(const float4*)(wsh + (kk + j) * 128 + tn * 4);
            #pragma unroll
            for (int i = 0; i < 4; ++i) {
                const float xi[4] = {xv[i].x, xv[i].y, xv[i].z, xv[i].w};
                #pragma unroll
                for (int j = 0; j < 4; ++j) {
                    acc[i].x = fmaf(xi[j], wv[j].x, acc[i].x);
                    acc[i].y = fmaf(xi[j], wv[j].y, acc[i].y);
                    acc[i].z = fmaf(xi[j], wv[j].z, acc[i].z);
                    acc[i].w = fmaf(xi[j], wv[j].w, acc[i].w);
                }
            }
        }
    }

    // epilogue: recombine logits_t / logits_n through LDS
    __syncthreads();
    float* outl = smem;                   // [64][128] = 32 KB
    #pragma unroll
    for (int i = 0; i < 4; ++i)
        *(float4*)(outl + (tm * 4 + i) * 128 + tn * 4) = acc[i];
    __syncthreads();

    const int ot = tid >> 3;              // token 0..63
    const int oe0 = (tid & 7) * 8;        // expert base
    #pragma unroll
    for (int q = 0; q < 8; ++q) {
        int e = oe0 + q;
        float lt = outl[ot * 128 + e];
        float ln = outl[ot * 128 + 64 + e];
        float sp = fmaxf(ln, 0.f) + log1pf(expf(-fabsf(ln)));  // stable softplus
        weight[(size_t)(t0 + ot) * NE + e] = lt + sp * noise[e];
    }
}

// ---------------------------------------------------------------------------
// Kernel 2: per-token top-8 -> masked softmax -> accumulate sumsoft[e];
// also raw per-expert column sums -> sumraw[e].
// grid 64 x block 256, one token per thread.
// ---------------------------------------------------------------------------
__global__ __launch_bounds__(256) void k_topk(const float* __restrict__ weight,
                                              float* __restrict__ sumraw,
                                              float* __restrict__ sumsoft) {
    __shared__ float lsoft[NE];
    const int tid = threadIdx.x;
    const int row = blockIdx.x * 256 + tid;

    if (tid < NE) lsoft[tid] = 0.f;

    // load this token's 64 weights into registers (static indexing only)
    float rv[NE];
    const float* rowp = weight + (size_t)row * NE;
    #pragma unroll
    for (int j = 0; j < 16; ++j) {
        float4 v = *(const float4*)(rowp + j * 4);
        rv[j * 4 + 0] = v.x; rv[j * 4 + 1] = v.y;
        rv[j * 4 + 2] = v.z; rv[j * 4 + 3] = v.w;
    }

    // top-8 via insertion (strict > keeps lowest index on ties, matching lax.top_k)
    float tv[KTOP]; int ti[KTOP];
    #pragma unroll
    for (int q = 0; q < KTOP; ++q) { tv[q] = -INFINITY; ti[q] = 0; }
    #pragma unroll
    for (int e = 0; e < NE; ++e) {
        float cv = rv[e]; int ci = e;
        #pragma unroll
        for (int q = 0; q < KTOP; ++q) {
            if (cv > tv[q]) {
                float t_ = tv[q]; int i_ = ti[q];
                tv[q] = cv; ti[q] = ci;
                cv = t_; ci = i_;
            }
        }
    }

    // masked softmax over the selected 8
    float m = tv[0];
    float p[KTOP];
    float den = 0.f;
    #pragma unroll
    for (int q = 0; q < KTOP; ++q) { p[q] = expf(tv[q] - m); den += p[q]; }
    float inv = 1.f / den;

    __syncthreads();                      // lsoft zero visible
    #pragma unroll
    for (int q = 0; q < KTOP; ++q) atomicAdd(&lsoft[ti[q]], p[q] * inv);

    // raw column sums (coalesced): col = tid&63, 64 rows per thread
    {
        const int col = tid & 63;
        const int rbase = blockIdx.x * 256 + (tid >> 6) * 64;
        float s = 0.f;
        for (int r = 0; r < 64; ++r)
            s += weight[(size_t)(rbase + r) * NE + col];
        atomicAdd(&sumraw[col], s);
    }

    __syncthreads();                      // all lsoft atomics done
    if (tid < NE) atomicAdd(&sumsoft[tid], lsoft[tid]);
}

// ---------------------------------------------------------------------------
// Kernel 3: finalize. mean top-8 + softmax -> out[0..15]; CV^2 -> out[16].
// ---------------------------------------------------------------------------
__global__ void k_final(const float* __restrict__ sumraw,
                        const float* __restrict__ sumsoft,
                        float* __restrict__ out) {
    if (threadIdx.x != 0 || blockIdx.x != 0) return;

    float mw[NE];
    for (int e = 0; e < NE; ++e) mw[e] = sumraw[e] * (1.f / (float)T_TOKENS);

    float tv[KTOP]; int ti[KTOP];
    for (int q = 0; q < KTOP; ++q) { tv[q] = -INFINITY; ti[q] = 0; }
    for (int e = 0; e < NE; ++e) {
        float cv = mw[e]; int ci = e;
        for (int q = 0; q < KTOP; ++q) {
            if (cv > tv[q]) {
                float t_ = tv[q]; int i_ = ti[q];
                tv[q] = cv; ti[q] = ci;
                cv = t_; ci = i_;
            }
        }
    }
    float m = tv[0];
    float p[KTOP]; float den = 0.f;
    for (int q = 0; q < KTOP; ++q) { p[q] = expf(tv[q] - m); den += p[q]; }
    for (int q = 0; q < KTOP; ++q) {
        out[q] = p[q] / den;
        out[KTOP + q] = (float)ti[q];
    }

    float s = 0.f;
    for (int e = 0; e < NE; ++e) s += sumsoft[e];
    float mean = s / (float)NE;
    float var = 0.f;
    for (int e = 0; e < NE; ++e) {
        float d = sumsoft[e] - mean;
        var += d * d;
    }
    var /= (float)(NE - 1);               // ddof=1
    out[16] = var / (mean * mean);
}

__global__ void k_zero(float* p, int n) {
    int i = blockIdx.x * blockDim.x + threadIdx.x;
    if (i < n) p[i] = 0.f;
}

extern "C" void kernel_launch(void* const* d_in, const int* in_sizes, int n_in,
                              void* d_out, int out_size, void* d_ws, size_t ws_size,
                              hipStream_t stream) {
    (void)in_sizes; (void)n_in; (void)out_size; (void)ws_size;
    const float* x     = (const float*)d_in[0];
    const float* wt    = (const float*)d_in[1];
    const float* wn    = (const float*)d_in[2];
    const float* noise = (const float*)d_in[3];
    float* out = (float*)d_out;

    float* weight  = (float*)d_ws;                       // [16384][64] fp32 = 4 MB
    float* sumraw  = weight + (size_t)T_TOKENS * NE;     // [64]
    float* sumsoft = sumraw + NE;                        // [64]

    k_zero<<<1, 128, 0, stream>>>(sumraw, 128);
    k_gemm<<<256, 512, 0, stream>>>(x, wt, wn, noise, weight);
    k_topk<<<64, 256, 0, stream>>>(weight, sumraw, sumsoft);
    k_final<<<1, 64, 0, stream>>>(sumraw, sumsoft, out);
}

// Round 2
// 136.196 us; speedup vs baseline: 1.5814x; 1.5814x over previous
//
#include <hip/hip_runtime.h>
#include <math.h>
#include <stdint.h>

#define H       2048
#define NE      64
#define KTOP    8
#define NTOK    16384

typedef __attribute__((ext_vector_type(8))) __bf16 bf16x8;
typedef __attribute__((ext_vector_type(8))) unsigned short us8;
typedef __attribute__((ext_vector_type(4))) float f32x4;

__device__ __forceinline__ unsigned short f2bf(float f) {
    unsigned u = __builtin_bit_cast(unsigned, f);
    return (unsigned short)((u + 0x7FFFu + ((u >> 16) & 1u)) >> 16);  // RNE
}

// ---------------------------------------------------------------------------
// k_prep: W fp32 -> bf16, concat [Wt;Wn] as wbf[128][2048]
// ---------------------------------------------------------------------------
__global__ __launch_bounds__(256) void k_prep(const float* __restrict__ Wt,
                                              const float* __restrict__ Wn,
                                              unsigned short* __restrict__ wbf) {
    int idx = (blockIdx.x * 256 + threadIdx.x) * 8;
    int row = idx >> 11;
    int col = idx & (H - 1);
    const float* src = (row < NE) ? (Wt + (size_t)row * H + col)
                                  : (Wn + (size_t)(row - NE) * H + col);
    float4 v0 = *(const float4*)src;
    float4 v1 = *(const float4*)(src + 4);
    us8 o;
    o[0] = f2bf(v0.x); o[1] = f2bf(v0.y); o[2] = f2bf(v0.z); o[3] = f2bf(v0.w);
    o[4] = f2bf(v1.x); o[5] = f2bf(v1.y); o[6] = f2bf(v1.z); o[7] = f2bf(v1.w);
    *(us8*)(wbf + idx) = o;
}

// ---------------------------------------------------------------------------
// k_main: MFMA bf16 GEMM (32 tokens x 128 cols per block, K=2048) with fused
// gate epilogue: weight -> per-token top8 -> masked softmax -> sums.
// Block 256 thr = 4 waves: wave = (mf = wid&1 token-frag, kp = wid>>1 K-half).
// LDS B tile is fragment-linear: slot (kh, nb, lane) holds
// W[nb*16 + (lane&15)][k0 + kh*32 + (lane>>4)*8 .. +7]  (16B per lane).
// ---------------------------------------------------------------------------
__global__ __launch_bounds__(256, 2) void k_main(const float* __restrict__ X,
                                                 const unsigned short* __restrict__ wbf,
                                                 const float* __restrict__ noise,
                                                 float* __restrict__ sumraw,
                                                 float* __restrict__ sumsoft) {
    __shared__ __align__(16) unsigned short Bl[2][2][8][64][8];  // 32 KB
    __shared__ float ep[32][66];                                 // 8.25 KB
    __shared__ float lsoft[NE];

    const int tid  = threadIdx.x;
    const int wid  = tid >> 6;
    const int lane = tid & 63;
    const int mf   = wid & 1;     // token fragment (16 tokens)
    const int kp   = wid >> 1;    // K parity (32-k half of each 64-k phase)
    const int lr   = lane & 15;
    const int lg   = lane >> 4;
    const int t0   = blockIdx.x * 32;

    if (tid < NE) lsoft[tid] = 0.f;

    f32x4 acc[8];
    #pragma unroll
    for (int i = 0; i < 8; ++i) acc[i] = (f32x4){0.f, 0.f, 0.f, 0.f};

    // B staging: 4 x global_load_lds(16B) per thread per phase, lane-linear LDS dest
    auto stage = [&](int buf, int p) {
        const int k0 = p * 64;
        #pragma unroll
        for (int i = 0; i < 4; ++i) {
            int s  = tid + 256 * i;
            int kh = s >> 9;
            int nb = (s >> 6) & 7;
            int ln = s & 63;
            const unsigned short* src =
                wbf + (size_t)(nb * 16 + (ln & 15)) * H + k0 + kh * 32 + (ln >> 4) * 8;
            unsigned short* dst = &Bl[buf][kh][nb][ln][0];
            __builtin_amdgcn_global_load_lds(
                (const __attribute__((address_space(1))) void*)src,
                (__attribute__((address_space(3))) void*)dst, 16, 0, 0);
        }
    };

    const float* xrow = X + (size_t)(t0 + mf * 16 + lr) * H + kp * 32 + lg * 8;

    stage(0, 0);
    float4 a0 = *(const float4*)(xrow);
    float4 a1 = *(const float4*)(xrow + 4);

    for (int p = 0; p < 32; ++p) {
        const int buf = p & 1;
        __syncthreads();                     // drains vmcnt -> stage(p) + prefetch ready
        if (p < 31) stage(buf ^ 1, p + 1);   // async into other buffer
        float4 n0 = a0, n1 = a1;
        if (p < 31) {
            n0 = *(const float4*)(xrow + (p + 1) * 64);
            n1 = *(const float4*)(xrow + (p + 1) * 64 + 4);
        }
        us8 au;
        au[0] = f2bf(a0.x); au[1] = f2bf(a0.y); au[2] = f2bf(a0.z); au[3] = f2bf(a0.w);
        au[4] = f2bf(a1.x); au[5] = f2bf(a1.y); au[6] = f2bf(a1.z); au[7] = f2bf(a1.w);
        bf16x8 af = __builtin_bit_cast(bf16x8, au);
        #pragma unroll
        for (int nb = 0; nb < 8; ++nb) {
            bf16x8 bfr = *(const bf16x8*)(&Bl[buf][kp][nb][lane][0]);
            acc[nb] = __builtin_amdgcn_mfma_f32_16x16x32_bf16(af, bfr, acc[nb], 0, 0, 0);
        }
        a0 = n0; a1 = n1;
    }

    // ---- K-split combine through LDS (reuse Bl space) ----
    __syncthreads();
    float* cb = (float*)&Bl[0][0][0][0][0];
    if (kp == 1) {
        #pragma unroll
        for (int nb = 0; nb < 8; ++nb)
            #pragma unroll
            for (int r = 0; r < 4; ++r)
                cb[((mf * 8 + nb) * 4 + r) * 64 + lane] = acc[nb][r];
    }
    __syncthreads();
    if (kp == 0) {
        float nz[4];
        #pragma unroll
        for (int nb = 0; nb < 4; ++nb) nz[nb] = noise[nb * 16 + lr];
        #pragma unroll
        for (int nb = 0; nb < 8; ++nb)
            #pragma unroll
            for (int r = 0; r < 4; ++r)
                acc[nb][r] += cb[((mf * 8 + nb) * 4 + r) * 64 + lane];
        // gate: weight = logit_t + softplus(logit_n) * noise[e]
        // C/D layout: col = lane&15, row = (lane>>4)*4 + r
        #pragma unroll
        for (int nb = 0; nb < 4; ++nb)
            #pragma unroll
            for (int r = 0; r < 4; ++r) {
                float lt  = acc[nb][r];
                float lnv = acc[nb + 4][r];
                float sp  = fmaxf(lnv, 0.f) + log1pf(expf(-fabsf(lnv)));
                ep[mf * 16 + lg * 4 + r][nb * 16 + lr] = lt + sp * nz[nb];
            }
    }
    __syncthreads();

    // ---- per-token top-8 + masked softmax (threads 0..31, one token each) ----
    if (tid < 32) {
        float tv[KTOP]; int ti[KTOP];
        #pragma unroll
        for (int q = 0; q < KTOP; ++q) { tv[q] = -INFINITY; ti[q] = 0; }
        for (int e = 0; e < NE; ++e) {
            float cv = ep[tid][e]; int ci = e;
            #pragma unroll
            for (int q = 0; q < KTOP; ++q) {
                if (cv > tv[q]) {
                    float t_ = tv[q]; int i_ = ti[q];
                    tv[q] = cv; ti[q] = ci;
                    cv = t_; ci = i_;
                }
            }
        }
        float m = tv[0], den = 0.f, pr[KTOP];
        #pragma unroll
        for (int q = 0; q < KTOP; ++q) { pr[q] = expf(tv[q] - m); den += pr[q]; }
        float inv = 1.f / den;
        #pragma unroll
        for (int q = 0; q < KTOP; ++q) atomicAdd(&lsoft[ti[q]], pr[q] * inv);
    }
    __syncthreads();

    // ---- per-expert sums -> global atomics (threads 0..63, one expert each) ----
    if (tid < NE) {
        float s = 0.f;
        for (int t = 0; t < 32; ++t) s += ep[t][tid];
        atomicAdd(&sumraw[tid], s);
        atomicAdd(&sumsoft[tid], lsoft[tid]);
    }
}

// ---------------------------------------------------------------------------
// k_final: mean top-8 + softmax -> out[0..15]; CV^2 -> out[16]
// ---------------------------------------------------------------------------
__global__ void k_final(const float* __restrict__ sumraw,
                        const float* __restrict__ sumsoft,
                        float* __restrict__ out) {
    if (threadIdx.x != 0 || blockIdx.x != 0) return;

    float mw[NE];
    for (int e = 0; e < NE; ++e) mw[e] = sumraw[e] * (1.f / (float)NTOK);

    float tv[KTOP]; int ti[KTOP];
    for (int q = 0; q < KTOP; ++q) { tv[q] = -INFINITY; ti[q] = 0; }
    for (int e = 0; e < NE; ++e) {
        float cv = mw[e]; int ci = e;
        for (int q = 0; q < KTOP; ++q) {
            if (cv > tv[q]) {
                float t_ = tv[q]; int i_ = ti[q];
                tv[q] = cv; ti[q] = ci;
                cv = t_; ci = i_;
            }
        }
    }
    float m = tv[0], den = 0.f, pr[KTOP];
    for (int q = 0; q < KTOP; ++q) { pr[q] = expf(tv[q] - m); den += pr[q]; }
    for (int q = 0; q < KTOP; ++q) {
        out[q] = pr[q] / den;
        out[KTOP + q] = (float)ti[q];
    }

    float s = 0.f;
    for (int e = 0; e < NE; ++e) s += sumsoft[e];
    float mean = s / (float)NE;
    float var = 0.f;
    for (int e = 0; e < NE; ++e) { float d = sumsoft[e] - mean; var += d * d; }
    var /= (float)(NE - 1);  // ddof=1
    out[16] = var / (mean * mean);
}

__global__ void k_zero(float* p, int n) {
    int i = blockIdx.x * blockDim.x + threadIdx.x;
    if (i < n) p[i] = 0.f;
}

extern "C" void kernel_launch(void* const* d_in, const int* in_sizes, int n_in,
                              void* d_out, int out_size, void* d_ws, size_t ws_size,
                              hipStream_t stream) {
    (void)in_sizes; (void)n_in; (void)out_size; (void)ws_size;
    const float* x     = (const float*)d_in[0];
    const float* wt    = (const float*)d_in[1];
    const float* wn    = (const float*)d_in[2];
    const float* noise = (const float*)d_in[3];
    float* out = (float*)d_out;

    float* sumraw  = (float*)d_ws;                     // [64]
    float* sumsoft = sumraw + NE;                      // [64]
    unsigned short* wbf = (unsigned short*)(sumsoft + NE);  // [128][2048] bf16, 512 KB

    k_zero<<<1, 128, 0, stream>>>(sumraw, 128);
    k_prep<<<128, 256, 0, stream>>>(wt, wn, wbf);
    k_main<<<512, 256, 0, stream>>>(x, wbf, noise, sumraw, sumsoft);
    k_final<<<1, 64, 0, stream>>>(sumraw, sumsoft, out);
}

// Round 3
// 118.222 us; speedup vs baseline: 1.8219x; 1.1520x over previous
//
#include <hip/hip_runtime.h>
#include <math.h>

#define H     2048
#define NE    64
#define KTOP  8
#define NTOK  16384

typedef __attribute__((ext_vector_type(8))) __bf16 bf16x8;
typedef __attribute__((ext_vector_type(8))) unsigned short us8;
typedef __attribute__((ext_vector_type(4))) float f32x4;

__device__ __forceinline__ unsigned short f2bf(float f) {
    unsigned u = __builtin_bit_cast(unsigned, f);
    return (unsigned short)((u + 0x7FFFu + ((u >> 16) & 1u)) >> 16);  // RNE
}

// ---------------------------------------------------------------------------
// k_prep: W fp32 -> bf16, swizzled fragment-linear:
// wbf2[(k32*8 + nb)*64 + ln][0..7] = W[nb*16 + (ln&15)][k32*32 + (ln>>4)*8 ..+7]
// so a wave's fragment load in k_main is 64 lanes x 16B = 1KB contiguous.
// Rows 0..63 of W = Wt, 64..127 = Wn. Also zeroes the sum buffers.
// ---------------------------------------------------------------------------
__global__ __launch_bounds__(256) void k_prep(const float* __restrict__ Wt,
                                              const float* __restrict__ Wn,
                                              unsigned short* __restrict__ wbf2,
                                              float* __restrict__ sums) {
    const int gid = blockIdx.x * 256 + threadIdx.x;   // 32768 threads
    if (blockIdx.x == 0 && threadIdx.x < 128) sums[threadIdx.x] = 0.f;

    const int ln  = gid & 63;
    const int nb  = (gid >> 6) & 7;
    const int k32 = gid >> 9;
    const int row = nb * 16 + (ln & 15);
    const int col = k32 * 32 + (ln >> 4) * 8;
    const float* src = (row < NE) ? (Wt + (size_t)row * H + col)
                                  : (Wn + (size_t)(row - NE) * H + col);
    float4 v0 = *(const float4*)src;
    float4 v1 = *(const float4*)(src + 4);
    us8 o;
    o[0] = f2bf(v0.x); o[1] = f2bf(v0.y); o[2] = f2bf(v0.z); o[3] = f2bf(v0.w);
    o[4] = f2bf(v1.x); o[5] = f2bf(v1.y); o[6] = f2bf(v1.z); o[7] = f2bf(v1.w);
    *(us8*)(wbf2 + (size_t)gid * 8) = o;
}

// ---------------------------------------------------------------------------
// k_main: barrier-free main loop. Block = 4 waves = same 16 tokens; wave w
// owns K-quarter [w*512, w*512+512). B fragments direct from L2 (pre-swizzled,
// coalesced); X depth-2 register prefetch; 8 MFMA per 32-k phase.
// Epilogue: 4-way K-combine in LDS -> gate -> top8/softmax -> global atomics.
// ---------------------------------------------------------------------------
__global__ __launch_bounds__(256, 4) void k_main(const float* __restrict__ X,
                                                 const unsigned short* __restrict__ wbf2,
                                                 const float* __restrict__ noise,
                                                 float* __restrict__ sumraw,
                                                 float* __restrict__ sumsoft) {
    __shared__ float cb[3][2048];     // waves 1..3 accumulator dump (24 KB)
    __shared__ float ep[16][68];      // weight[16 tokens][64 experts] (+pad)
    __shared__ float lsoft[NE];

    const int tid  = threadIdx.x;
    const int wid  = tid >> 6;
    const int lane = tid & 63;
    const int lr   = lane & 15;
    const int lg   = lane >> 4;
    const int t0   = blockIdx.x * 16;

    if (wid == 1) lsoft[lane] = 0.f;

    const float* xp = X + (size_t)(t0 + lr) * H + wid * 512 + lg * 8;
    const unsigned short* wp = wbf2 + ((size_t)wid * 16 * 8) * 512 + lane * 8;

    f32x4 acc[8];
    #pragma unroll
    for (int i = 0; i < 8; ++i) acc[i] = (f32x4){0.f, 0.f, 0.f, 0.f};

    float4 x00 = *(const float4*)(xp);
    float4 x01 = *(const float4*)(xp + 4);
    float4 x10 = *(const float4*)(xp + 32);
    float4 x11 = *(const float4*)(xp + 36);

    auto body = [&](int p, float4& c0, float4& c1) {
        us8 au;
        au[0] = f2bf(c0.x); au[1] = f2bf(c0.y); au[2] = f2bf(c0.z); au[3] = f2bf(c0.w);
        au[4] = f2bf(c1.x); au[5] = f2bf(c1.y); au[6] = f2bf(c1.z); au[7] = f2bf(c1.w);
        bf16x8 af = __builtin_bit_cast(bf16x8, au);
        if (p + 2 < 16) {                       // depth-2 X prefetch
            c0 = *(const float4*)(xp + (p + 2) * 32);
            c1 = *(const float4*)(xp + (p + 2) * 32 + 4);
        }
        const unsigned short* bp = wp + (size_t)(p * 8) * 512;
        #pragma unroll
        for (int nb = 0; nb < 8; ++nb) {
            bf16x8 b = *(const bf16x8*)(bp + nb * 512);
            acc[nb] = __builtin_amdgcn_mfma_f32_16x16x32_bf16(af, b, acc[nb], 0, 0, 0);
        }
    };

    for (int p = 0; p < 16; p += 2) {
        body(p, x00, x01);
        body(p + 1, x10, x11);
    }

    // ---- 4-way K combine ----
    if (wid > 0) {
        #pragma unroll
        for (int nb = 0; nb < 8; ++nb)
            #pragma unroll
            for (int r = 0; r < 4; ++r)
                cb[wid - 1][(nb * 4 + r) * 64 + lane] = acc[nb][r];
    }
    __syncthreads();

    if (wid == 0) {
        #pragma unroll
        for (int nb = 0; nb < 8; ++nb)
            #pragma unroll
            for (int r = 0; r < 4; ++r) {
                int idx = (nb * 4 + r) * 64 + lane;
                acc[nb][r] += cb[0][idx] + cb[1][idx] + cb[2][idx];
            }
        float nz[4];
        #pragma unroll
        for (int nb = 0; nb < 4; ++nb) nz[nb] = noise[nb * 16 + lr];
        // gate: weight = logit_t + softplus(logit_n) * noise[e]
        // C/D layout: expert col = lane&15 (+nb*16), token row = (lane>>4)*4 + r
        #pragma unroll
        for (int nb = 0; nb < 4; ++nb)
            #pragma unroll
            for (int r = 0; r < 4; ++r) {
                float lt  = acc[nb][r];
                float lnv = acc[nb + 4][r];
                float sp  = fmaxf(lnv, 0.f) + log1pf(expf(-fabsf(lnv)));
                ep[lg * 4 + r][nb * 16 + lr] = lt + sp * nz[nb];
            }
    }
    __syncthreads();

    // ---- per-token top-8 + masked softmax (wave 0, lanes 0..15) ----
    if (wid == 0 && lane < 16) {
        float tv[KTOP]; int ti[KTOP];
        #pragma unroll
        for (int q = 0; q < KTOP; ++q) { tv[q] = -INFINITY; ti[q] = 0; }
        for (int e = 0; e < NE; ++e) {
            float cv = ep[lane][e]; int ci = e;
            #pragma unroll
            for (int q = 0; q < KTOP; ++q) {
                if (cv > tv[q]) {
                    float t_ = tv[q]; int i_ = ti[q];
                    tv[q] = cv; ti[q] = ci;
                    cv = t_; ci = i_;
                }
            }
        }
        float m = tv[0], den = 0.f, pr[KTOP];
        #pragma unroll
        for (int q = 0; q < KTOP; ++q) { pr[q] = expf(tv[q] - m); den += pr[q]; }
        float inv = 1.f / den;
        #pragma unroll
        for (int q = 0; q < KTOP; ++q) atomicAdd(&lsoft[ti[q]], pr[q] * inv);
    }
    // ---- raw per-expert sums (wave 1, one expert per lane) ----
    if (wid == 1) {
        float s = 0.f;
        #pragma unroll
        for (int t = 0; t < 16; ++t) s += ep[t][lane];
        atomicAdd(&sumraw[lane], s);
    }
    __syncthreads();
    if (wid == 2) atomicAdd(&sumsoft[lane], lsoft[lane]);
}

// ---------------------------------------------------------------------------
// k_final: mean top-8 + softmax -> out[0..15]; CV^2 -> out[16]
// ---------------------------------------------------------------------------
__global__ void k_final(const float* __restrict__ sumraw,
                        const float* __restrict__ sumsoft,
                        float* __restrict__ out) {
    if (threadIdx.x != 0 || blockIdx.x != 0) return;

    float mw[NE];
    for (int e = 0; e < NE; ++e) mw[e] = sumraw[e] * (1.f / (float)NTOK);

    float tv[KTOP]; int ti[KTOP];
    for (int q = 0; q < KTOP; ++q) { tv[q] = -INFINITY; ti[q] = 0; }
    for (int e = 0; e < NE; ++e) {
        float cv = mw[e]; int ci = e;
        for (int q = 0; q < KTOP; ++q) {
            if (cv > tv[q]) {
                float t_ = tv[q]; int i_ = ti[q];
                tv[q] = cv; ti[q] = ci;
                cv = t_; ci = i_;
            }
        }
    }
    float m = tv[0], den = 0.f, pr[KTOP];
    for (int q = 0; q < KTOP; ++q) { pr[q] = expf(tv[q] - m); den += pr[q]; }
    for (int q = 0; q < KTOP; ++q) {
        out[q] = pr[q] / den;
        out[KTOP + q] = (float)ti[q];
    }

    float s = 0.f;
    for (int e = 0; e < NE; ++e) s += sumsoft[e];
    float mean = s / (float)NE;
    float var = 0.f;
    for (int e = 0; e < NE; ++e) { float d = sumsoft[e] - mean; var += d * d; }
    var /= (float)(NE - 1);  // ddof=1
    out[16] = var / (mean * mean);
}

extern "C" void kernel_launch(void* const* d_in, const int* in_sizes, int n_in,
                              void* d_out, int out_size, void* d_ws, size_t ws_size,
                              hipStream_t stream) {
    (void)in_sizes; (void)n_in; (void)out_size; (void)ws_size;
    const float* x     = (const float*)d_in[0];
    const float* wt    = (const float*)d_in[1];
    const float* wn    = (const float*)d_in[2];
    const float* noise = (const float*)d_in[3];
    float* out = (float*)d_out;

    float* sumraw  = (float*)d_ws;                          // [64]
    float* sumsoft = sumraw + NE;                           // [64]
    unsigned short* wbf2 = (unsigned short*)(sumsoft + NE); // [128][2048] bf16 swizzled

    k_prep<<<128, 256, 0, stream>>>(wt, wn, wbf2, sumraw);
    k_main<<<1024, 256, 0, stream>>>(x, wbf2, noise, sumraw, sumsoft);
    k_final<<<1, 64, 0, stream>>>(sumraw, sumsoft, out);
}

// Round 4
// 110.649 us; speedup vs baseline: 1.9466x; 1.0684x over previous
//
#include <hip/hip_runtime.h>
#include <math.h>

#define H     2048
#define NE    64
#define KTOP  8
#define NTOK  16384

typedef __attribute__((ext_vector_type(8))) __bf16 bf16x8;
typedef __attribute__((ext_vector_type(8))) unsigned short us8;
typedef __attribute__((ext_vector_type(4))) float f32x4;

__device__ __forceinline__ unsigned short f2bf(float f) {
    unsigned u = __builtin_bit_cast(unsigned, f);
    return (unsigned short)((u + 0x7FFFu + ((u >> 16) & 1u)) >> 16);  // RNE
}

// ---------------------------------------------------------------------------
// k_prep: W fp32 -> bf16, swizzled fragment-linear:
// wbf2[(k32*8 + nb)*64 + ln][0..7] = W[nb*16 + (ln&15)][k32*32 + (ln>>4)*8 ..+7]
// so a wave's fragment load in k_main is 64 lanes x 16B = 1KB contiguous.
// ---------------------------------------------------------------------------
__global__ __launch_bounds__(256) void k_prep(const float* __restrict__ Wt,
                                              const float* __restrict__ Wn,
                                              unsigned short* __restrict__ wbf2,
                                              float* __restrict__ sums) {
    const int gid = blockIdx.x * 256 + threadIdx.x;   // 32768 threads
    if (blockIdx.x == 0 && threadIdx.x < 128) sums[threadIdx.x] = 0.f;

    const int ln  = gid & 63;
    const int nb  = (gid >> 6) & 7;
    const int k32 = gid >> 9;
    const int row = nb * 16 + (ln & 15);
    const int col = k32 * 32 + (ln >> 4) * 8;
    const float* src = (row < NE) ? (Wt + (size_t)row * H + col)
                                  : (Wn + (size_t)(row - NE) * H + col);
    float4 v0 = *(const float4*)src;
    float4 v1 = *(const float4*)(src + 4);
    us8 o;
    o[0] = f2bf(v0.x); o[1] = f2bf(v0.y); o[2] = f2bf(v0.z); o[3] = f2bf(v0.w);
    o[4] = f2bf(v1.x); o[5] = f2bf(v1.y); o[6] = f2bf(v1.z); o[7] = f2bf(v1.w);
    *(us8*)(wbf2 + (size_t)gid * 8) = o;
}

// ---------------------------------------------------------------------------
// k_main: barrier-free main loop, explicit register pipelining.
// Block = 4 waves = same 16 tokens; wave w owns K-quarter [w*512, w*512+512).
// B fragments: register double-buffer bb[2][8], loads for phase p+1 issued
// before phase p MFMAs. X: depth-2 float4 prefetch. Native bf16 casts
// (v_cvt_pk_bf16_f32). Fully unrolled -> all indices compile-time.
// ---------------------------------------------------------------------------
__global__ __launch_bounds__(256, 3) void k_main(const float* __restrict__ X,
                                                 const unsigned short* __restrict__ wbf2,
                                                 const float* __restrict__ noise,
                                                 float* __restrict__ sumraw,
                                                 float* __restrict__ sumsoft) {
    __shared__ float cb[3][2048];     // waves 1..3 accumulator dump (24 KB)
    __shared__ float ep[16][68];      // weight[16 tokens][64 experts] (+pad)
    __shared__ float lsoft[NE];

    const int tid  = threadIdx.x;
    const int wid  = tid >> 6;
    const int lane = tid & 63;
    const int lr   = lane & 15;
    const int lg   = lane >> 4;
    const int t0   = blockIdx.x * 16;

    if (wid == 1) lsoft[lane] = 0.f;

    const float* xp = X + (size_t)(t0 + lr) * H + wid * 512 + lg * 8;
    const unsigned short* wp = wbf2 + (size_t)wid * 16 * 4096 + (size_t)lane * 8;

    f32x4 acc[8];
    #pragma unroll
    for (int i = 0; i < 8; ++i) acc[i] = (f32x4){0.f, 0.f, 0.f, 0.f};

    bf16x8 bb[2][8];                  // B double-buffer (64 VGPR)
    float4 xa[2][2];                  // X depth-2 prefetch

    #pragma unroll
    for (int nb = 0; nb < 8; ++nb)
        bb[0][nb] = *(const bf16x8*)(wp + (size_t)nb * 512);
    xa[0][0] = *(const float4*)(xp);
    xa[0][1] = *(const float4*)(xp + 4);
    xa[1][0] = *(const float4*)(xp + 32);
    xa[1][1] = *(const float4*)(xp + 36);

    #pragma unroll
    for (int p = 0; p < 16; ++p) {
        const int cu = p & 1;         // compile-time (fully unrolled)
        const int nx = cu ^ 1;
        // issue next-phase B loads first: phase p MFMAs never wait on them
        if (p < 15) {
            const unsigned short* bp = wp + (size_t)(p + 1) * 4096;
            #pragma unroll
            for (int nb = 0; nb < 8; ++nb)
                bb[nx][nb] = *(const bf16x8*)(bp + (size_t)nb * 512);
        }
        // convert current X (native casts -> v_cvt_pk_bf16_f32)
        float4 c0 = xa[cu][0], c1 = xa[cu][1];
        bf16x8 af;
        af[0] = (__bf16)c0.x; af[1] = (__bf16)c0.y;
        af[2] = (__bf16)c0.z; af[3] = (__bf16)c0.w;
        af[4] = (__bf16)c1.x; af[5] = (__bf16)c1.y;
        af[6] = (__bf16)c1.z; af[7] = (__bf16)c1.w;
        // refill the just-consumed X slot with phase p+2
        if (p + 2 < 16) {
            xa[cu][0] = *(const float4*)(xp + (p + 2) * 32);
            xa[cu][1] = *(const float4*)(xp + (p + 2) * 32 + 4);
        }
        #pragma unroll
        for (int nb = 0; nb < 8; ++nb)
            acc[nb] = __builtin_amdgcn_mfma_f32_16x16x32_bf16(af, bb[cu][nb], acc[nb], 0, 0, 0);
    }

    // ---- 4-way K combine ----
    if (wid > 0) {
        #pragma unroll
        for (int nb = 0; nb < 8; ++nb)
            #pragma unroll
            for (int r = 0; r < 4; ++r)
                cb[wid - 1][(nb * 4 + r) * 64 + lane] = acc[nb][r];
    }
    __syncthreads();

    if (wid == 0) {
        #pragma unroll
        for (int nb = 0; nb < 8; ++nb)
            #pragma unroll
            for (int r = 0; r < 4; ++r) {
                int idx = (nb * 4 + r) * 64 + lane;
                acc[nb][r] += cb[0][idx] + cb[1][idx] + cb[2][idx];
            }
        float nz[4];
        #pragma unroll
        for (int nb = 0; nb < 4; ++nb) nz[nb] = noise[nb * 16 + lr];
        // gate: weight = logit_t + softplus(logit_n) * noise[e]
        // C/D layout: expert col = lane&15 (+nb*16), token row = (lane>>4)*4 + r
        #pragma unroll
        for (int nb = 0; nb < 4; ++nb)
            #pragma unroll
            for (int r = 0; r < 4; ++r) {
                float lt  = acc[nb][r];
                float lnv = acc[nb + 4][r];
                float sp  = fmaxf(lnv, 0.f) + log1pf(expf(-fabsf(lnv)));
                ep[lg * 4 + r][nb * 16 + lr] = lt + sp * nz[nb];
            }
    }
    __syncthreads();

    // ---- per-token top-8 + masked softmax (wave 0, lanes 0..15) ----
    if (wid == 0 && lane < 16) {
        float tv[KTOP]; int ti[KTOP];
        #pragma unroll
        for (int q = 0; q < KTOP; ++q) { tv[q] = -INFINITY; ti[q] = 0; }
        for (int e = 0; e < NE; ++e) {
            float cv = ep[lane][e]; int ci = e;
            #pragma unroll
            for (int q = 0; q < KTOP; ++q) {
                if (cv > tv[q]) {
                    float t_ = tv[q]; int i_ = ti[q];
                    tv[q] = cv; ti[q] = ci;
                    cv = t_; ci = i_;
                }
            }
        }
        float m = tv[0], den = 0.f, pr[KTOP];
        #pragma unroll
        for (int q = 0; q < KTOP; ++q) { pr[q] = expf(tv[q] - m); den += pr[q]; }
        float inv = 1.f / den;
        #pragma unroll
        for (int q = 0; q < KTOP; ++q) atomicAdd(&lsoft[ti[q]], pr[q] * inv);
    }
    // ---- raw per-expert sums (wave 1, one expert per lane) ----
    if (wid == 1) {
        float s = 0.f;
        #pragma unroll
        for (int t = 0; t < 16; ++t) s += ep[t][lane];
        atomicAdd(&sumraw[lane], s);
    }
    __syncthreads();
    if (wid == 2) atomicAdd(&sumsoft[lane], lsoft[lane]);
}

// ---------------------------------------------------------------------------
// k_final: mean top-8 + softmax -> out[0..15]; CV^2 -> out[16]
// ---------------------------------------------------------------------------
__global__ void k_final(const float* __restrict__ sumraw,
                        const float* __restrict__ sumsoft,
                        float* __restrict__ out) {
    if (threadIdx.x != 0 || blockIdx.x != 0) return;

    float mw[NE];
    for (int e = 0; e < NE; ++e) mw[e] = sumraw[e] * (1.f / (float)NTOK);

    float tv[KTOP]; int ti[KTOP];
    for (int q = 0; q < KTOP; ++q) { tv[q] = -INFINITY; ti[q] = 0; }
    for (int e = 0; e < NE; ++e) {
        float cv = mw[e]; int ci = e;
        for (int q = 0; q < KTOP; ++q) {
            if (cv > tv[q]) {
                float t_ = tv[q]; int i_ = ti[q];
                tv[q] = cv; ti[q] = ci;
                cv = t_; ci = i_;
            }
        }
    }
    float m = tv[0], den = 0.f, pr[KTOP];
    for (int q = 0; q < KTOP; ++q) { pr[q] = expf(tv[q] - m); den += pr[q]; }
    for (int q = 0; q < KTOP; ++q) {
        out[q] = pr[q] / den;
        out[KTOP + q] = (float)ti[q];
    }

    float s = 0.f;
    for (int e = 0; e < NE; ++e) s += sumsoft[e];
    float mean = s / (float)NE;
    float var = 0.f;
    for (int e = 0; e < NE; ++e) { float d = sumsoft[e] - mean; var += d * d; }
    var /= (float)(NE - 1);  // ddof=1
    out[16] = var / (mean * mean);
}

extern "C" void kernel_launch(void* const* d_in, const int* in_sizes, int n_in,
                              void* d_out, int out_size, void* d_ws, size_t ws_size,
                              hipStream_t stream) {
    (void)in_sizes; (void)n_in; (void)out_size; (void)ws_size;
    const float* x     = (const float*)d_in[0];
    const float* wt    = (const float*)d_in[1];
    const float* wn    = (const float*)d_in[2];
    const float* noise = (const float*)d_in[3];
    float* out = (float*)d_out;

    float* sumraw  = (float*)d_ws;                          // [64]
    float* sumsoft = sumraw + NE;                           // [64]
    unsigned short* wbf2 = (unsigned short*)(sumsoft + NE); // [128][2048] bf16 swizzled

    k_prep<<<128, 256, 0, stream>>>(wt, wn, wbf2, sumraw);
    k_main<<<1024, 256, 0, stream>>>(x, wbf2, noise, sumraw, sumsoft);
    k_final<<<1, 64, 0, stream>>>(sumraw, sumsoft, out);
}